// Round 4
// baseline (818.779 us; speedup 1.0000x reference)
//
#include <hip/hip_runtime.h>
#include <math.h>

#define NUM_USERS 100000
#define NUM_ITEMS 50000
#define NN 150000               // total nodes
#define EE 1200000              // total directed edges (2 * E_DIR)
#define W_US 32                 // ELL width, user destinations (Poisson(6) tail ~0)
#define W_IT 40                 // ELL width, item destinations (Poisson(12) tail ~1e-10)
#define ITEM_BASE ((size_t)NUM_USERS * W_US)             // in entries
#define N_ELL (ITEM_BASE + (size_t)NUM_ITEMS * W_IT)     // 4.7M entries, 37.6MB... 41.6MB

typedef unsigned short ushort_t;
typedef unsigned int uint_t;

__device__ __forceinline__ ushort_t f2b(float f) {       // fp32 -> bf16 RNE
    uint_t b = __float_as_uint(f);
    return (ushort_t)((b + 0x7FFFu + ((b >> 16) & 1u)) >> 16);
}
__device__ __forceinline__ float b2f(ushort_t u) {       // bf16 -> fp32 exact
    return __uint_as_float(((uint_t)u) << 16);
}

__device__ __forceinline__ size_t ell_base(int node, int* w) {
    if (node < NUM_USERS) { *w = W_US; return (size_t)node * W_US; }
    *w = W_IT; return ITEM_BASE + (size_t)(node - NUM_USERS) * W_IT;
}

// ---- fused edge MLP + ELL scatter -------------------------------------------
// ew = sigmoid(relu(f@w1+b1)@w2+b2); k=cnt[col]++; ell[base(col)+k]={row, ew}
__global__ void mlp_fill_kernel(const float* __restrict__ feats,
                                const float* __restrict__ w1,
                                const float* __restrict__ b1,
                                const float* __restrict__ w2,
                                const float* __restrict__ b2,
                                const int* __restrict__ row,
                                const int* __restrict__ col,
                                int* __restrict__ cnt,
                                int2* __restrict__ ell) {
    __shared__ float sw1[256];
    __shared__ float sb1[32];
    __shared__ float sw2[32];
    __shared__ float sb2;
    int t = threadIdx.x;
    sw1[t] = w1[t];
    if (t < 32) { sb1[t] = b1[t]; sw2[t] = w2[t]; }
    if (t == 0) sb2 = b2[0];
    __syncthreads();
    int e = blockIdx.x * 256 + t;
    if (e >= EE) return;
    int r = row[e], c = col[e];
    const float4* fp = (const float4*)(feats + (size_t)e * 8);
    float4 fa = fp[0], fb = fp[1];
    float f[8] = {fa.x, fa.y, fa.z, fa.w, fb.x, fb.y, fb.z, fb.w};
    float s = sb2;
#pragma unroll
    for (int j = 0; j < 32; ++j) {
        float h = sb1[j];
#pragma unroll
        for (int i = 0; i < 8; ++i) h = fmaf(f[i], sw1[i * 32 + j], h);
        h = fmaxf(h, 0.f);
        s = fmaf(h, sw2[j], s);
    }
    float w = 1.f / (1.f + expf(-s));
    int wid; size_t base = ell_base(c, &wid);
    int k = atomicAdd(&cnt[c], 1);
    if (k < wid) ell[base + k] = make_int2(r, __float_as_int(w));
}

// ---- dinv[i] = deg>0 ? 1/sqrt(deg) : 0, deg = sum of own ELL weights --------
__global__ void dinv_kernel(const int2* __restrict__ ell,
                            const int* __restrict__ cnt,
                            float* __restrict__ dinv) {
    unsigned t = blockIdx.x * 256u + threadIdx.x;
    unsigned node = t >> 6, lane = t & 63u;
    if (node >= NN) return;
    int wid; size_t base = ell_base((int)node, &wid);
    int m = cnt[node]; if (m > wid) m = wid;
    float w = ((int)lane < m) ? __int_as_float(ell[base + lane].y) : 0.f;
#pragma unroll
    for (int off = 32; off > 0; off >>= 1) w += __shfl_xor(w, off, 64);
    if (lane == 0) dinv[node] = (w > 0.f) ? (1.f / sqrtf(w)) : 0.f;
}

// ---- z0 = dinv>0 ? dinv*l2norm(feat) : l2norm(feat); out = z0 (fp32) --------
__global__ void init_x_kernel(const float* __restrict__ user_w,
                              const float* __restrict__ audio,
                              const float* __restrict__ artist_w,
                              const float* __restrict__ album_w,
                              const int* __restrict__ artist_ids,
                              const int* __restrict__ album_ids,
                              const float* __restrict__ dinv,
                              ushort_t* __restrict__ z0,
                              float* __restrict__ out) {
    unsigned t = blockIdx.x * 256u + threadIdx.x;
    unsigned node = t >> 6, lane = t & 63u;
    if (node >= NN) return;
    float v;
    if (node < NUM_USERS) {
        v = user_w[node * 64u + lane];
    } else {
        unsigned j = node - NUM_USERS;
        unsigned a = (unsigned)artist_ids[j], b = (unsigned)album_ids[j];
        v = fmaf(0.44f, artist_w[a * 64u + lane] + album_w[b * 64u + lane],
                 0.3f * audio[j * 64u + lane]);
    }
    float s = v * v;
#pragma unroll
    for (int off = 32; off > 0; off >>= 1) s += __shfl_xor(s, off, 64);
    float n = fmaxf(sqrtf(s), 1e-12f);
    float o = v / n;
    float d = dinv[node];
    float zv = (d > 0.f) ? d * o : o;     // isolated nodes keep x0 (never gathered)
    z0[node * 64u + lane] = f2b(zv);
    out[node * 64u + lane] = zv;
}

// ---- SpMM layer: z_out[c] = dinv_c^2 * sum_e ew_e * z_in[row_e] -------------
// FINAL=0: store z_out bf16, out += z_out (fp32).
// FINAL=1: v = out + z_out; out = l2norm(v) in-wave; set align_loss.
template <int FINAL>
__global__ void spmm_kernel(const ushort_t* __restrict__ zin,
                            const int2* __restrict__ ell,
                            const int* __restrict__ cnt,
                            const float* __restrict__ dinv,
                            ushort_t* __restrict__ zout,
                            float* __restrict__ out) {
    unsigned t = blockIdx.x * 256u + threadIdx.x;
    unsigned node = t >> 6, lane = t & 63u;
    if (node >= NN) return;
    int wid; size_t base = ell_base((int)node, &wid);
    int m = cnt[node]; if (m > wid) m = wid;
    int r = 0; float w = 0.f;
    if ((int)lane < m) {
        int2 p = ell[base + lane];
        r = p.x; w = __int_as_float(p.y);
    }
    float a = 0.f;
    int mr = (m + 7) & ~7;               // lanes >= m carry w=0 -> contribute 0
    for (int j = 0; j < mr; j += 8) {
        int   rj[8]; float wj[8], vj[8];
#pragma unroll
        for (int u = 0; u < 8; ++u) { rj[u] = __shfl(r, j + u, 64); wj[u] = __shfl(w, j + u, 64); }
#pragma unroll
        for (int u = 0; u < 8; ++u) vj[u] = b2f(zin[(unsigned)rj[u] * 64u + lane]);
#pragma unroll
        for (int u = 0; u < 8; ++u) a = fmaf(wj[u], vj[u], a);
    }
    float d = dinv[node];
    float z = a * d * d;
    unsigned i = node * 64u + lane;
    if (FINAL) {
        float v = out[i] + z;
        float s = v * v;
#pragma unroll
        for (int off = 32; off > 0; off >>= 1) s += __shfl_xor(s, off, 64);
        float n = fmaxf(sqrtf(s), 1e-12f);
        out[i] = v / n;
        if (blockIdx.x == 0 && threadIdx.x == 0) out[(size_t)NN * 64u] = 0.f;
    } else {
        zout[i] = f2b(z);
        out[i] += z;
    }
}

extern "C" void kernel_launch(void* const* d_in, const int* in_sizes, int n_in,
                              void* d_out, int out_size, void* d_ws, size_t ws_size,
                              hipStream_t stream) {
    const float* user_w     = (const float*)d_in[0];
    const float* audio      = (const float*)d_in[1];
    const float* artist_w   = (const float*)d_in[2];
    const float* album_w    = (const float*)d_in[3];
    const float* w1         = (const float*)d_in[4];
    const float* b1         = (const float*)d_in[5];
    const float* w2         = (const float*)d_in[6];
    const float* b2         = (const float*)d_in[7];
    const float* feats      = (const float*)d_in[8];
    const int*   row        = (const int*)d_in[9];
    const int*   col        = row + EE;
    const int*   artist_ids = (const int*)d_in[10];
    const int*   album_ids  = (const int*)d_in[11];
    float* out = (float*)d_out;

    // workspace: cnt[NN] | dinv[NN] | ell[N_ELL int2] | za, zb (bf16 NN*64) ~81MB
    int*      cnt  = (int*)d_ws;
    float*    dinv = (float*)(cnt + NN);
    int2*     ell  = (int2*)(dinv + NN);
    ushort_t* za   = (ushort_t*)(ell + N_ELL);
    ushort_t* zb   = za + (size_t)NN * 64;

    hipMemsetAsync(cnt, 0, NN * sizeof(int), stream);

    mlp_fill_kernel<<<(EE + 255) / 256, 256, 0, stream>>>(feats, w1, b1, w2, b2,
                                                          row, col, cnt, ell);
    dinv_kernel<<<(NN * 64) / 256, 256, 0, stream>>>(ell, cnt, dinv);
    init_x_kernel<<<(NN * 64) / 256, 256, 0, stream>>>(user_w, audio, artist_w, album_w,
                                                       artist_ids, album_ids, dinv, za, out);
    spmm_kernel<0><<<(NN * 64) / 256, 256, 0, stream>>>(za, ell, cnt, dinv, zb, out);
    spmm_kernel<0><<<(NN * 64) / 256, 256, 0, stream>>>(zb, ell, cnt, dinv, za, out);
    spmm_kernel<1><<<(NN * 64) / 256, 256, 0, stream>>>(za, ell, cnt, dinv, zb, out);
}

// Round 5
// 439.258 us; speedup vs baseline: 1.8640x; 1.8640x over previous
//
#include <hip/hip_runtime.h>
#include <math.h>

#define NUM_USERS 100000
#define NUM_ITEMS 50000
#define NN 150000               // total nodes
#define EE 1200000              // total directed edges (2 * E_DIR)
#define NB 586                  // ceil(NN/256) scan blocks
#define NNP (NB * 256)          // padded node count = 150016

typedef unsigned short ushort_t;
typedef unsigned int uint_t;

__device__ __forceinline__ ushort_t f2b(float f) {       // fp32 -> bf16 RNE
    uint_t b = __float_as_uint(f);
    return (ushort_t)((b + 0x7FFFu + ((b >> 16) & 1u)) >> 16);
}
__device__ __forceinline__ float b2f(ushort_t u) {       // bf16 -> fp32 exact
    return __uint_as_float(((uint_t)u) << 16);
}

// ---- count + rank: ONE atomic per edge; rank = return value -----------------
__global__ void count_rank_kernel(const int* __restrict__ col,
                                  int* __restrict__ counts,
                                  int* __restrict__ rank) {
    int e = blockIdx.x * 256 + threadIdx.x;
    if (e >= EE) return;
    rank[e] = atomicAdd(&counts[col[e]], 1);
}

// ---- scan step 1: per-block exclusive scan of counts; block totals ----------
__global__ void scan1_kernel(const int* __restrict__ counts,
                             int* __restrict__ offs,
                             int* __restrict__ partials) {
    int i = blockIdx.x * 256 + threadIdx.x;
    int lane = threadIdx.x & 63;
    int v = counts[i];                           // [NN,NNP) pre-zeroed
    int s = v;
#pragma unroll
    for (int off = 1; off < 64; off <<= 1) {
        int u = __shfl_up(s, off, 64);
        if (lane >= off) s += u;
    }
    __shared__ int wsum[4];
    if (lane == 63) wsum[threadIdx.x >> 6] = s;
    __syncthreads();
    int add = 0;
    for (int w = 0; w < (threadIdx.x >> 6); ++w) add += wsum[w];
    offs[i] = s - v + add;
    if (threadIdx.x == 255) partials[blockIdx.x] = s + add;
}

// ---- scan step 2: single-block exclusive scan of the NB partials ------------
__global__ void scan2_kernel(int* __restrict__ partials, int nb) {
    __shared__ int wsum[4];
    __shared__ int carry;
    if (threadIdx.x == 0) carry = 0;
    __syncthreads();
    int lane = threadIdx.x & 63;
    for (int base = 0; base < nb; base += 256) {
        int i = base + threadIdx.x;
        int v = (i < nb) ? partials[i] : 0;
        int s = v;
#pragma unroll
        for (int off = 1; off < 64; off <<= 1) {
            int u = __shfl_up(s, off, 64);
            if (lane >= off) s += u;
        }
        if (lane == 63) wsum[threadIdx.x >> 6] = s;
        __syncthreads();
        int add = 0;
        for (int w = 0; w < (threadIdx.x >> 6); ++w) add += wsum[w];
        int excl = s - v + add + carry;
        if (i < nb) partials[i] = excl;
        __syncthreads();
        if (threadIdx.x == 255) carry = excl + v;
        __syncthreads();
    }
}

// ---- scan step 3: add block bases -------------------------------------------
__global__ void scan3_kernel(int* __restrict__ offs,
                             const int* __restrict__ partials) {
    int i = blockIdx.x * 256 + threadIdx.x;
    offs[i] = offs[i] + partials[blockIdx.x];
}

// ---- fused MLP + atomic-free CSR fill ---------------------------------------
// packed[offs[col] + rank] = {row, sigmoid(relu(f@w1+b1)@w2+b2)}
__global__ void mlp_fill_kernel(const float* __restrict__ feats,
                                const float* __restrict__ w1,
                                const float* __restrict__ b1,
                                const float* __restrict__ w2,
                                const float* __restrict__ b2,
                                const int* __restrict__ row,
                                const int* __restrict__ col,
                                const int* __restrict__ rank,
                                const int* __restrict__ offs,
                                int2* __restrict__ packed) {
    __shared__ float sw1[256];
    __shared__ float sb1[32];
    __shared__ float sw2[32];
    __shared__ float sb2;
    int t = threadIdx.x;
    sw1[t] = w1[t];
    if (t < 32) { sb1[t] = b1[t]; sw2[t] = w2[t]; }
    if (t == 0) sb2 = b2[0];
    __syncthreads();
    int e = blockIdx.x * 256 + t;
    if (e >= EE) return;
    const float4* fp = (const float4*)(feats + (size_t)e * 8);
    float4 fa = fp[0], fb = fp[1];
    float f[8] = {fa.x, fa.y, fa.z, fa.w, fb.x, fb.y, fb.z, fb.w};
    float s = sb2;
#pragma unroll
    for (int j = 0; j < 32; ++j) {
        float h = sb1[j];
#pragma unroll
        for (int i = 0; i < 8; ++i) h = fmaf(f[i], sw1[i * 32 + j], h);
        h = fmaxf(h, 0.f);
        s = fmaf(h, sw2[j], s);
    }
    float w = 1.f / (1.f + expf(-s));
    int slot = offs[col[e]] + rank[e];
    packed[slot] = make_int2(row[e], __float_as_int(w));
}

// ---- dinv[i] from own CSR segment (coalesced, atomic-free) ------------------
__global__ void dinv_kernel(const int2* __restrict__ packed,
                            const int* __restrict__ offs,
                            float* __restrict__ dinv) {
    unsigned t = blockIdx.x * 256u + threadIdx.x;
    unsigned node = t >> 6, lane = t & 63u;
    if (node >= NN) return;
    int beg = offs[node], end = offs[node + 1];
    float d = 0.f;
    for (int k = beg + (int)lane; k < end; k += 64) d += __int_as_float(packed[k].y);
#pragma unroll
    for (int off = 32; off > 0; off >>= 1) d += __shfl_xor(d, off, 64);
    if (lane == 0) dinv[node] = (d > 0.f) ? (1.f / sqrtf(d)) : 0.f;
}

// ---- z0 = (dinv>0 ? dinv : 1) * l2norm(feat), bf16 --------------------------
__global__ void init_z_kernel(const float* __restrict__ user_w,
                              const float* __restrict__ audio,
                              const float* __restrict__ artist_w,
                              const float* __restrict__ album_w,
                              const int* __restrict__ artist_ids,
                              const int* __restrict__ album_ids,
                              const float* __restrict__ dinv,
                              ushort_t* __restrict__ z0) {
    unsigned t = blockIdx.x * 256u + threadIdx.x;
    unsigned node = t >> 6, lane = t & 63u;
    if (node >= NN) return;
    float v;
    if (node < NUM_USERS) {
        v = user_w[node * 64u + lane];
    } else {
        unsigned j = node - NUM_USERS;
        unsigned a = (unsigned)artist_ids[j], b = (unsigned)album_ids[j];
        v = fmaf(0.44f, artist_w[a * 64u + lane] + album_w[b * 64u + lane],
                 0.3f * audio[j * 64u + lane]);
    }
    float s = v * v;
#pragma unroll
    for (int off = 32; off > 0; off >>= 1) s += __shfl_xor(s, off, 64);
    float n = fmaxf(sqrtf(s), 1e-12f);
    float d = dinv[node];
    float scale = (d > 0.f) ? d : 1.f;
    z0[node * 64u + lane] = f2b(scale * v / n);
}

// ---- SpMM layer in z-space: zout[c] = dinv_c^2 * sum ew * zin[row] ----------
__global__ void spmm_kernel(const ushort_t* __restrict__ zin,
                            const int2* __restrict__ packed,
                            const int* __restrict__ offs,
                            const float* __restrict__ dinv,
                            ushort_t* __restrict__ zout) {
    unsigned t = blockIdx.x * 256u + threadIdx.x;
    unsigned node = t >> 6, lane = t & 63u;
    if (node >= NN) return;
    int beg = offs[node], end = offs[node + 1];
    float a = 0.f;
    for (int base = beg; base < end; base += 64) {
        int m = end - base; if (m > 64) m = 64;
        int r = 0; float w = 0.f;
        if ((int)lane < m) {
            int2 p = packed[base + lane];
            r = p.x; w = __int_as_float(p.y);
        }
        int mr = (m + 7) & ~7;            // lanes >= m carry w=0 -> contribute 0
        for (int j = 0; j < mr; j += 8) {
            int rj[8]; float wj[8], vj[8];
#pragma unroll
            for (int u = 0; u < 8; ++u) {
                rj[u] = __shfl(r, j + u, 64);
                wj[u] = __shfl(w, j + u, 64);
            }
#pragma unroll
            for (int u = 0; u < 8; ++u) vj[u] = b2f(zin[(unsigned)rj[u] * 64u + lane]);
#pragma unroll
            for (int u = 0; u < 8; ++u) a = fmaf(wj[u], vj[u], a);
        }
    }
    float d = dinv[node];
    zout[node * 64u + lane] = f2b(a * d * d);
}

// ---- out = l2norm(z0+z1+z2+z3); align_loss = 0 ------------------------------
// (per-node positive scale r and the /4 cancel inside l2norm)
__global__ void finalize_kernel(const ushort_t* __restrict__ z0,
                                const ushort_t* __restrict__ z1,
                                const ushort_t* __restrict__ z2,
                                const ushort_t* __restrict__ z3,
                                float* __restrict__ out) {
    unsigned t = blockIdx.x * 256u + threadIdx.x;
    unsigned node = t >> 6, lane = t & 63u;
    if (node >= NN) return;
    unsigned i = node * 64u + lane;
    float v = b2f(z0[i]) + b2f(z1[i]) + b2f(z2[i]) + b2f(z3[i]);
    float s = v * v;
#pragma unroll
    for (int off = 32; off > 0; off >>= 1) s += __shfl_xor(s, off, 64);
    float n = fmaxf(sqrtf(s), 1e-12f);
    out[i] = v / n;
    if (t == 0) out[(size_t)NN * 64u] = 0.f;     // align_loss
}

extern "C" void kernel_launch(void* const* d_in, const int* in_sizes, int n_in,
                              void* d_out, int out_size, void* d_ws, size_t ws_size,
                              hipStream_t stream) {
    const float* user_w     = (const float*)d_in[0];
    const float* audio      = (const float*)d_in[1];
    const float* artist_w   = (const float*)d_in[2];
    const float* album_w    = (const float*)d_in[3];
    const float* w1         = (const float*)d_in[4];
    const float* b1         = (const float*)d_in[5];
    const float* w2         = (const float*)d_in[6];
    const float* b2         = (const float*)d_in[7];
    const float* feats      = (const float*)d_in[8];
    const int*   row        = (const int*)d_in[9];
    const int*   col        = row + EE;
    const int*   artist_ids = (const int*)d_in[10];
    const int*   album_ids  = (const int*)d_in[11];
    float* out = (float*)d_out;

    // workspace (4B units): counts[NNP] offs[NNP+16] partials[1024] rank[EE]
    //                        dinv[NN] packed[EE int2] z0..z3 bf16  ~93.1 MB
    int*      counts   = (int*)d_ws;
    int*      offs     = counts + NNP;
    int*      partials = offs + NNP + 16;
    int*      rank     = partials + 1024;
    float*    dinv     = (float*)(rank + EE);
    int2*     packed   = (int2*)(dinv + NN);
    ushort_t* z0       = (ushort_t*)(packed + EE);
    ushort_t* z1       = z0 + (size_t)NN * 64;
    ushort_t* z2       = z1 + (size_t)NN * 64;
    ushort_t* z3       = z2 + (size_t)NN * 64;

    hipMemsetAsync(counts, 0, NNP * sizeof(int), stream);

    count_rank_kernel<<<(EE + 255) / 256, 256, 0, stream>>>(col, counts, rank);
    scan1_kernel<<<NB, 256, 0, stream>>>(counts, offs, partials);
    scan2_kernel<<<1, 256, 0, stream>>>(partials, NB);
    scan3_kernel<<<NB, 256, 0, stream>>>(offs, partials);
    mlp_fill_kernel<<<(EE + 255) / 256, 256, 0, stream>>>(feats, w1, b1, w2, b2,
                                                          row, col, rank, offs, packed);
    dinv_kernel<<<(NN * 64) / 256, 256, 0, stream>>>(packed, offs, dinv);
    init_z_kernel<<<(NN * 64) / 256, 256, 0, stream>>>(user_w, audio, artist_w, album_w,
                                                       artist_ids, album_ids, dinv, z0);
    spmm_kernel<<<(NN * 64) / 256, 256, 0, stream>>>(z0, packed, offs, dinv, z1);
    spmm_kernel<<<(NN * 64) / 256, 256, 0, stream>>>(z1, packed, offs, dinv, z2);
    spmm_kernel<<<(NN * 64) / 256, 256, 0, stream>>>(z2, packed, offs, dinv, z3);
    finalize_kernel<<<(NN * 64) / 256, 256, 0, stream>>>(z0, z1, z2, z3, out);
}

// Round 6
// 421.089 us; speedup vs baseline: 1.9444x; 1.0431x over previous
//
#include <hip/hip_runtime.h>
#include <math.h>

#define NUM_USERS 100000
#define NUM_ITEMS 50000
#define NN 150000               // total nodes
#define EE 1200000              // total directed edges (2 * E_DIR)
#define NB 586                  // ceil(NN/256) scan blocks
#define NNP (NB * 256)          // padded node count = 150016

typedef unsigned short ushort_t;
typedef unsigned int uint_t;

__device__ __forceinline__ ushort_t f2b(float f) {       // fp32 -> bf16 RNE
    uint_t b = __float_as_uint(f);
    return (ushort_t)((b + 0x7FFFu + ((b >> 16) & 1u)) >> 16);
}
__device__ __forceinline__ float b2f(ushort_t u) {       // bf16 -> fp32 exact
    return __uint_as_float(((uint_t)u) << 16);
}

// ---- fused edge MLP + count/rank (ONE atomic per edge) ----------------------
// ew[e] = sigmoid(relu(f@w1+b1)@w2+b2); rank[e] = counts[col[e]]++
__global__ void mlp_count_kernel(const float* __restrict__ feats,
                                 const float* __restrict__ w1,
                                 const float* __restrict__ b1,
                                 const float* __restrict__ w2,
                                 const float* __restrict__ b2,
                                 const int* __restrict__ col,
                                 float* __restrict__ ew,
                                 int* __restrict__ rank,
                                 int* __restrict__ counts) {
    __shared__ float sw1[256];
    __shared__ float sb1[32];
    __shared__ float sw2[32];
    __shared__ float sb2;
    int t = threadIdx.x;
    sw1[t] = w1[t];
    if (t < 32) { sb1[t] = b1[t]; sw2[t] = w2[t]; }
    if (t == 0) sb2 = b2[0];
    __syncthreads();
    int e = blockIdx.x * 256 + t;
    if (e >= EE) return;
    int c = col[e];
    const float4* fp = (const float4*)(feats + (size_t)e * 8);
    float4 fa = fp[0], fb = fp[1];
    float f[8] = {fa.x, fa.y, fa.z, fa.w, fb.x, fb.y, fb.z, fb.w};
    float s = sb2;
#pragma unroll
    for (int j = 0; j < 32; ++j) {
        float h = sb1[j];
#pragma unroll
        for (int i = 0; i < 8; ++i) h = fmaf(f[i], sw1[i * 32 + j], h);
        h = fmaxf(h, 0.f);
        s = fmaf(h, sw2[j], s);
    }
    ew[e] = 1.f / (1.f + expf(-s));
    rank[e] = atomicAdd(&counts[c], 1);
}

// ---- scan step 1: per-block exclusive scan of counts; block totals ----------
__global__ void scan1_kernel(const int* __restrict__ counts,
                             int* __restrict__ offs,
                             int* __restrict__ partials) {
    int i = blockIdx.x * 256 + threadIdx.x;
    int lane = threadIdx.x & 63;
    int v = counts[i];                           // [NN,NNP) pre-zeroed
    int s = v;
#pragma unroll
    for (int off = 1; off < 64; off <<= 1) {
        int u = __shfl_up(s, off, 64);
        if (lane >= off) s += u;
    }
    __shared__ int wsum[4];
    if (lane == 63) wsum[threadIdx.x >> 6] = s;
    __syncthreads();
    int add = 0;
    for (int w = 0; w < (threadIdx.x >> 6); ++w) add += wsum[w];
    offs[i] = s - v + add;
    if (threadIdx.x == 255) partials[blockIdx.x] = s + add;
}

// ---- scan step 2: single-block exclusive scan of the NB partials ------------
__global__ void scan2_kernel(int* __restrict__ partials, int nb) {
    __shared__ int wsum[4];
    __shared__ int carry;
    if (threadIdx.x == 0) carry = 0;
    __syncthreads();
    int lane = threadIdx.x & 63;
    for (int base = 0; base < nb; base += 256) {
        int i = base + threadIdx.x;
        int v = (i < nb) ? partials[i] : 0;
        int s = v;
#pragma unroll
        for (int off = 1; off < 64; off <<= 1) {
            int u = __shfl_up(s, off, 64);
            if (lane >= off) s += u;
        }
        if (lane == 63) wsum[threadIdx.x >> 6] = s;
        __syncthreads();
        int add = 0;
        for (int w = 0; w < (threadIdx.x >> 6); ++w) add += wsum[w];
        int excl = s - v + add + carry;
        if (i < nb) partials[i] = excl;
        __syncthreads();
        if (threadIdx.x == 255) carry = excl + v;
        __syncthreads();
    }
}

// ---- scan step 3: add block bases -------------------------------------------
__global__ void scan3_kernel(int* __restrict__ offs,
                             const int* __restrict__ partials) {
    int i = blockIdx.x * 256 + threadIdx.x;
    offs[i] = offs[i] + partials[blockIdx.x];
}

// ---- atomic-free CSR fill: packed[offs[col]+rank] = {row, ew} ---------------
__global__ void fill_kernel(const float* __restrict__ ew,
                            const int* __restrict__ rank,
                            const int* __restrict__ row,
                            const int* __restrict__ col,
                            const int* __restrict__ offs,
                            int2* __restrict__ packed) {
    int e = blockIdx.x * 256 + threadIdx.x;
    if (e >= EE) return;
    int slot = offs[col[e]] + rank[e];
    packed[slot] = make_int2(row[e], __float_as_int(ew[e]));
}

// ---- fused dinv + z0: dinv from own CSR segment; z0=(dinv|1)*l2norm(feat) ---
__global__ void dinv_init_kernel(const int2* __restrict__ packed,
                                 const int* __restrict__ offs,
                                 const float* __restrict__ user_w,
                                 const float* __restrict__ audio,
                                 const float* __restrict__ artist_w,
                                 const float* __restrict__ album_w,
                                 const int* __restrict__ artist_ids,
                                 const int* __restrict__ album_ids,
                                 float* __restrict__ dinv,
                                 ushort_t* __restrict__ z0) {
    unsigned t = blockIdx.x * 256u + threadIdx.x;
    unsigned node = t >> 6, lane = t & 63u;
    if (node >= NN) return;
    int beg = offs[node], end = offs[node + 1];
    float dsum = 0.f;
    for (int k = beg + (int)lane; k < end; k += 64) dsum += __int_as_float(packed[k].y);
#pragma unroll
    for (int off = 32; off > 0; off >>= 1) dsum += __shfl_xor(dsum, off, 64);
    float d = (dsum > 0.f) ? (1.f / sqrtf(dsum)) : 0.f;
    if (lane == 0) dinv[node] = d;

    float v;
    if (node < NUM_USERS) {
        v = user_w[node * 64u + lane];
    } else {
        unsigned j = node - NUM_USERS;
        unsigned a = (unsigned)artist_ids[j], b = (unsigned)album_ids[j];
        v = fmaf(0.44f, artist_w[a * 64u + lane] + album_w[b * 64u + lane],
                 0.3f * audio[j * 64u + lane]);
    }
    float s = v * v;
#pragma unroll
    for (int off = 32; off > 0; off >>= 1) s += __shfl_xor(s, off, 64);
    float n = fmaxf(sqrtf(s), 1e-12f);
    float scale = (d > 0.f) ? d : 1.f;
    z0[node * 64u + lane] = f2b(scale * v / n);
}

// ---- gather core: a = sum ew * zin[row] over node's CSR segment -------------
// Straight-line clamped batches (8 or 16) for deg<=16; loop for bigger.
__device__ __forceinline__ float gather_node(const ushort_t* __restrict__ zin,
                                             const int2* __restrict__ packed,
                                             int beg, int end, unsigned lane) {
    float a = 0.f;
    for (int base = beg; base < end; base += 64) {
        int m = end - base; if (m > 64) m = 64;
        if (m == 0) break;
        int r = 0; float w = 0.f;
        if ((int)lane < m) {
            int2 p = packed[base + lane];
            r = p.x; w = __int_as_float(p.y);
        }
        if (m <= 8) {                      // wave-uniform branch
            int rj[8]; float wj[8], vj[8];
#pragma unroll
            for (int u = 0; u < 8; ++u) {
                int idx = (u < m) ? u : (m - 1);
                rj[u] = __shfl(r, idx, 64);
                wj[u] = __shfl(w, u, 64);  // lanes >= m carry 0
            }
#pragma unroll
            for (int u = 0; u < 8; ++u) vj[u] = b2f(zin[(unsigned)rj[u] * 64u + lane]);
#pragma unroll
            for (int u = 0; u < 8; ++u) a = fmaf(wj[u], vj[u], a);
        } else if (m <= 16) {
            int rj[16]; float wj[16], vj[16];
#pragma unroll
            for (int u = 0; u < 16; ++u) {
                int idx = (u < m) ? u : (m - 1);
                rj[u] = __shfl(r, idx, 64);
                wj[u] = __shfl(w, u, 64);
            }
#pragma unroll
            for (int u = 0; u < 16; ++u) vj[u] = b2f(zin[(unsigned)rj[u] * 64u + lane]);
#pragma unroll
            for (int u = 0; u < 16; ++u) a = fmaf(wj[u], vj[u], a);
        } else {
            int mr = (m + 7) & ~7;         // lanes >= m carry w=0, r=0
            for (int j = 0; j < mr; j += 8) {
                int rj[8]; float wj[8], vj[8];
#pragma unroll
                for (int u = 0; u < 8; ++u) {
                    rj[u] = __shfl(r, j + u, 64);
                    wj[u] = __shfl(w, j + u, 64);
                }
#pragma unroll
                for (int u = 0; u < 8; ++u) vj[u] = b2f(zin[(unsigned)rj[u] * 64u + lane]);
#pragma unroll
                for (int u = 0; u < 8; ++u) a = fmaf(wj[u], vj[u], a);
            }
        }
    }
    return a;
}

// ---- SpMM layer in z-space: zout[c] = dinv_c^2 * sum ew * zin[row] ----------
__global__ void spmm_kernel(const ushort_t* __restrict__ zin,
                            const int2* __restrict__ packed,
                            const int* __restrict__ offs,
                            const float* __restrict__ dinv,
                            ushort_t* __restrict__ zout) {
    unsigned t = blockIdx.x * 256u + threadIdx.x;
    unsigned node = t >> 6, lane = t & 63u;
    if (node >= NN) return;
    float a = gather_node(zin, packed, offs[node], offs[node + 1], lane);
    float d = dinv[node];
    zout[node * 64u + lane] = f2b(a * d * d);
}

// ---- final layer fused with l2norm: out = l2norm(z0+z1+z2+z3) ---------------
__global__ void spmm_final_kernel(const ushort_t* __restrict__ z0,
                                  const ushort_t* __restrict__ z1,
                                  const ushort_t* __restrict__ z2,
                                  const int2* __restrict__ packed,
                                  const int* __restrict__ offs,
                                  const float* __restrict__ dinv,
                                  float* __restrict__ out) {
    unsigned t = blockIdx.x * 256u + threadIdx.x;
    unsigned node = t >> 6, lane = t & 63u;
    if (node >= NN) return;
    float a = gather_node(z2, packed, offs[node], offs[node + 1], lane);
    float d = dinv[node];
    unsigned i = node * 64u + lane;
    float v = b2f(z0[i]) + b2f(z1[i]) + b2f(z2[i]) + a * d * d;
    float s = v * v;
#pragma unroll
    for (int off = 32; off > 0; off >>= 1) s += __shfl_xor(s, off, 64);
    float n = fmaxf(sqrtf(s), 1e-12f);
    out[i] = v / n;
    if (t == 0) out[(size_t)NN * 64u] = 0.f;     // align_loss
}

extern "C" void kernel_launch(void* const* d_in, const int* in_sizes, int n_in,
                              void* d_out, int out_size, void* d_ws, size_t ws_size,
                              hipStream_t stream) {
    const float* user_w     = (const float*)d_in[0];
    const float* audio      = (const float*)d_in[1];
    const float* artist_w   = (const float*)d_in[2];
    const float* album_w    = (const float*)d_in[3];
    const float* w1         = (const float*)d_in[4];
    const float* b1         = (const float*)d_in[5];
    const float* w2         = (const float*)d_in[6];
    const float* b2         = (const float*)d_in[7];
    const float* feats      = (const float*)d_in[8];
    const int*   row        = (const int*)d_in[9];
    const int*   col        = row + EE;
    const int*   artist_ids = (const int*)d_in[10];
    const int*   album_ids  = (const int*)d_in[11];
    float* out = (float*)d_out;

    // workspace (4B units): counts[NNP] offs[NNP+16] partials[1024] rank[EE]
    //                        ew[EE] dinv[NN] packed[EE int2] z0..z2 bf16 ~79MB
    int*      counts   = (int*)d_ws;
    int*      offs     = counts + NNP;
    int*      partials = offs + NNP + 16;
    int*      rank     = partials + 1024;
    float*    ew       = (float*)(rank + EE);
    float*    dinv     = ew + EE;
    int2*     packed   = (int2*)(dinv + NN);
    ushort_t* z0       = (ushort_t*)(packed + EE);
    ushort_t* z1       = z0 + (size_t)NN * 64;
    ushort_t* z2       = z1 + (size_t)NN * 64;

    hipMemsetAsync(counts, 0, NNP * sizeof(int), stream);

    mlp_count_kernel<<<(EE + 255) / 256, 256, 0, stream>>>(feats, w1, b1, w2, b2,
                                                           col, ew, rank, counts);
    scan1_kernel<<<NB, 256, 0, stream>>>(counts, offs, partials);
    scan2_kernel<<<1, 256, 0, stream>>>(partials, NB);
    scan3_kernel<<<NB, 256, 0, stream>>>(offs, partials);
    fill_kernel<<<(EE + 255) / 256, 256, 0, stream>>>(ew, rank, row, col, offs, packed);
    dinv_init_kernel<<<(NN * 64) / 256, 256, 0, stream>>>(packed, offs,
                                                          user_w, audio, artist_w, album_w,
                                                          artist_ids, album_ids, dinv, z0);
    spmm_kernel<<<(NN * 64) / 256, 256, 0, stream>>>(z0, packed, offs, dinv, z1);
    spmm_kernel<<<(NN * 64) / 256, 256, 0, stream>>>(z1, packed, offs, dinv, z2);
    spmm_final_kernel<<<(NN * 64) / 256, 256, 0, stream>>>(z0, z1, z2, packed, offs,
                                                           dinv, out);
}

// Round 7
// 325.704 us; speedup vs baseline: 2.5139x; 1.2929x over previous
//
#include <hip/hip_runtime.h>
#include <math.h>

#define NUM_USERS 100000
#define NUM_ITEMS 50000
#define NN 150000               // total nodes
#define EE 1200000              // total directed edges (2 * E_DIR)
#define NB 586                  // ceil(NN/256) scan blocks
#define NNP (NB * 256)          // padded node count = 150016
#define G8_BLOCKS 4688          // ceil(NN*8/256) for 8-lane-per-node kernels

typedef unsigned short ushort_t;
typedef unsigned int uint_t;

__device__ __forceinline__ uint_t pack2(float lo, float hi) {   // 2x fp32 -> bf16x2 RNE
    uint_t a = __float_as_uint(lo);
    uint_t b = __float_as_uint(hi);
    a = (a + 0x7FFFu + ((a >> 16) & 1u)) >> 16;
    b = (b + 0x7FFFu + ((b >> 16) & 1u)) & 0xFFFF0000u;
    return a | b;
}
__device__ __forceinline__ float lo16(uint_t x) { return __uint_as_float(x << 16); }
__device__ __forceinline__ float hi16(uint_t x) { return __uint_as_float(x & 0xFFFF0000u); }

// ---- fused edge MLP + count/rank (ONE atomic per edge) ----------------------
__global__ void mlp_count_kernel(const float* __restrict__ feats,
                                 const float* __restrict__ w1,
                                 const float* __restrict__ b1,
                                 const float* __restrict__ w2,
                                 const float* __restrict__ b2,
                                 const int* __restrict__ col,
                                 float* __restrict__ ew,
                                 int* __restrict__ rank,
                                 int* __restrict__ counts) {
    __shared__ float sw1[256];
    __shared__ float sb1[32];
    __shared__ float sw2[32];
    __shared__ float sb2;
    int t = threadIdx.x;
    sw1[t] = w1[t];
    if (t < 32) { sb1[t] = b1[t]; sw2[t] = w2[t]; }
    if (t == 0) sb2 = b2[0];
    __syncthreads();
    int e = blockIdx.x * 256 + t;
    if (e >= EE) return;
    int c = col[e];
    const float4* fp = (const float4*)(feats + (size_t)e * 8);
    float4 fa = fp[0], fb = fp[1];
    float f[8] = {fa.x, fa.y, fa.z, fa.w, fb.x, fb.y, fb.z, fb.w};
    float s = sb2;
#pragma unroll
    for (int j = 0; j < 32; ++j) {
        float h = sb1[j];
#pragma unroll
        for (int i = 0; i < 8; ++i) h = fmaf(f[i], sw1[i * 32 + j], h);
        h = fmaxf(h, 0.f);
        s = fmaf(h, sw2[j], s);
    }
    ew[e] = 1.f / (1.f + expf(-s));
    rank[e] = atomicAdd(&counts[c], 1);
}

// ---- scan step 1: per-block exclusive scan of counts; block totals ----------
__global__ void scan1_kernel(const int* __restrict__ counts,
                             int* __restrict__ offs,
                             int* __restrict__ partials) {
    int i = blockIdx.x * 256 + threadIdx.x;
    int lane = threadIdx.x & 63;
    int v = counts[i];                           // [NN,NNP) pre-zeroed
    int s = v;
#pragma unroll
    for (int off = 1; off < 64; off <<= 1) {
        int u = __shfl_up(s, off, 64);
        if (lane >= off) s += u;
    }
    __shared__ int wsum[4];
    if (lane == 63) wsum[threadIdx.x >> 6] = s;
    __syncthreads();
    int add = 0;
    for (int w = 0; w < (threadIdx.x >> 6); ++w) add += wsum[w];
    offs[i] = s - v + add;
    if (threadIdx.x == 255) partials[blockIdx.x] = s + add;
}

// ---- scan step 2: single-block exclusive scan of the NB partials ------------
__global__ void scan2_kernel(int* __restrict__ partials, int nb) {
    __shared__ int wsum[4];
    __shared__ int carry;
    if (threadIdx.x == 0) carry = 0;
    __syncthreads();
    int lane = threadIdx.x & 63;
    for (int base = 0; base < nb; base += 256) {
        int i = base + threadIdx.x;
        int v = (i < nb) ? partials[i] : 0;
        int s = v;
#pragma unroll
        for (int off = 1; off < 64; off <<= 1) {
            int u = __shfl_up(s, off, 64);
            if (lane >= off) s += u;
        }
        if (lane == 63) wsum[threadIdx.x >> 6] = s;
        __syncthreads();
        int add = 0;
        for (int w = 0; w < (threadIdx.x >> 6); ++w) add += wsum[w];
        int excl = s - v + add + carry;
        if (i < nb) partials[i] = excl;
        __syncthreads();
        if (threadIdx.x == 255) carry = excl + v;
        __syncthreads();
    }
}

// ---- scan step 3: add block bases -------------------------------------------
__global__ void scan3_kernel(int* __restrict__ offs,
                             const int* __restrict__ partials) {
    int i = blockIdx.x * 256 + threadIdx.x;
    offs[i] = offs[i] + partials[blockIdx.x];
}

// ---- atomic-free CSR fill: packed[offs[col]+rank] = {row, ew} ---------------
__global__ void fill_kernel(const float* __restrict__ ew,
                            const int* __restrict__ rank,
                            const int* __restrict__ row,
                            const int* __restrict__ col,
                            const int* __restrict__ offs,
                            int2* __restrict__ packed) {
    int e = blockIdx.x * 256 + threadIdx.x;
    if (e >= EE) return;
    int slot = offs[col[e]] + rank[e];
    packed[slot] = make_int2(row[e], __float_as_int(ew[e]));
}

// ---- gather core: 8 lanes per node, 16B loads; a0/a1 = cols 8c..8c+7 --------
__device__ __forceinline__ void gather_node8(const ushort_t* __restrict__ zin,
                                             const int2* __restrict__ packed,
                                             int beg, int end, unsigned c,
                                             float4& a0, float4& a1) {
    for (int base = beg; base < end; base += 8) {
        int m = end - base; if (m > 8) m = 8;
        int r = 0; float w = 0.f;
        if ((int)c < m) {
            int2 p = packed[base + (int)c];
            r = p.x; w = __int_as_float(p.y);
        }
        int rj[8]; float wj[8]; uint4 vj[8];
#pragma unroll
        for (int u = 0; u < 8; ++u) {
            int idx = (u < m) ? u : (m - 1);       // clamp: re-read last valid row
            rj[u] = __shfl(r, idx, 8);
            wj[u] = __shfl(w, u, 8);               // lanes >= m carry w=0
        }
#pragma unroll
        for (int u = 0; u < 8; ++u)
            vj[u] = *(const uint4*)(zin + (size_t)(uint_t)rj[u] * 64u + c * 8u);
#pragma unroll
        for (int u = 0; u < 8; ++u) {
            float ww = wj[u]; uint4 v = vj[u];
            a0.x = fmaf(ww, lo16(v.x), a0.x);
            a0.y = fmaf(ww, hi16(v.x), a0.y);
            a0.z = fmaf(ww, lo16(v.y), a0.z);
            a0.w = fmaf(ww, hi16(v.y), a0.w);
            a1.x = fmaf(ww, lo16(v.z), a1.x);
            a1.y = fmaf(ww, hi16(v.z), a1.y);
            a1.z = fmaf(ww, lo16(v.w), a1.z);
            a1.w = fmaf(ww, hi16(v.w), a1.w);
        }
    }
}

// ---- fused dinv + z0 (8 lanes per node) -------------------------------------
__global__ void dinv_init_kernel(const int2* __restrict__ packed,
                                 const int* __restrict__ offs,
                                 const float* __restrict__ user_w,
                                 const float* __restrict__ audio,
                                 const float* __restrict__ artist_w,
                                 const float* __restrict__ album_w,
                                 const int* __restrict__ artist_ids,
                                 const int* __restrict__ album_ids,
                                 float* __restrict__ dinv,
                                 ushort_t* __restrict__ z0) {
    unsigned t = blockIdx.x * 256u + threadIdx.x;
    unsigned node = t >> 3, c = t & 7u;
    if (node >= NN) return;
    int beg = offs[node], end = offs[node + 1];
    float ds = 0.f;
    for (int k = beg + (int)c; k < end; k += 8) ds += __int_as_float(packed[k].y);
    ds += __shfl_xor(ds, 1, 8);
    ds += __shfl_xor(ds, 2, 8);
    ds += __shfl_xor(ds, 4, 8);
    float d = (ds > 0.f) ? rsqrtf(ds) : 0.f;
    if (c == 0) dinv[node] = d;

    size_t ri = (size_t)node * 64u + c * 8u;
    float v[8];
    if (node < NUM_USERS) {
        float4 x0 = *(const float4*)(user_w + ri);
        float4 x1 = *(const float4*)(user_w + ri + 4);
        v[0]=x0.x; v[1]=x0.y; v[2]=x0.z; v[3]=x0.w;
        v[4]=x1.x; v[5]=x1.y; v[6]=x1.z; v[7]=x1.w;
    } else {
        unsigned j = node - NUM_USERS;
        unsigned aid = (unsigned)artist_ids[j], bid = (unsigned)album_ids[j];
        const float* ap = artist_w + (size_t)aid * 64u + c * 8u;
        const float* bp = album_w  + (size_t)bid * 64u + c * 8u;
        const float* up = audio    + (size_t)j   * 64u + c * 8u;
        float4 A0 = *(const float4*)ap, A1 = *(const float4*)(ap + 4);
        float4 B0 = *(const float4*)bp, B1 = *(const float4*)(bp + 4);
        float4 U0 = *(const float4*)up, U1 = *(const float4*)(up + 4);
        v[0] = fmaf(0.44f, A0.x + B0.x, 0.3f * U0.x);
        v[1] = fmaf(0.44f, A0.y + B0.y, 0.3f * U0.y);
        v[2] = fmaf(0.44f, A0.z + B0.z, 0.3f * U0.z);
        v[3] = fmaf(0.44f, A0.w + B0.w, 0.3f * U0.w);
        v[4] = fmaf(0.44f, A1.x + B1.x, 0.3f * U1.x);
        v[5] = fmaf(0.44f, A1.y + B1.y, 0.3f * U1.y);
        v[6] = fmaf(0.44f, A1.z + B1.z, 0.3f * U1.z);
        v[7] = fmaf(0.44f, A1.w + B1.w, 0.3f * U1.w);
    }
    float s = 0.f;
#pragma unroll
    for (int k = 0; k < 8; ++k) s = fmaf(v[k], v[k], s);
    s += __shfl_xor(s, 1, 8);
    s += __shfl_xor(s, 2, 8);
    s += __shfl_xor(s, 4, 8);
    float rn = rsqrtf(fmaxf(s, 1e-24f));          // == 1/max(||x||,1e-12)
    float scale = ((d > 0.f) ? d : 1.f) * rn;
    uint4 o;
    o.x = pack2(v[0] * scale, v[1] * scale);
    o.y = pack2(v[2] * scale, v[3] * scale);
    o.z = pack2(v[4] * scale, v[5] * scale);
    o.w = pack2(v[6] * scale, v[7] * scale);
    *(uint4*)(z0 + ri) = o;
}

// ---- SpMM layer in z-space: zout[n] = dinv_n^2 * sum ew * zin[row] ----------
__global__ void spmm_kernel(const ushort_t* __restrict__ zin,
                            const int2* __restrict__ packed,
                            const int* __restrict__ offs,
                            const float* __restrict__ dinv,
                            ushort_t* __restrict__ zout) {
    unsigned t = blockIdx.x * 256u + threadIdx.x;
    unsigned node = t >> 3, c = t & 7u;
    if (node >= NN) return;
    float4 a0 = make_float4(0,0,0,0), a1 = make_float4(0,0,0,0);
    gather_node8(zin, packed, offs[node], offs[node + 1], c, a0, a1);
    float d = dinv[node], dd = d * d;
    uint4 o;
    o.x = pack2(a0.x * dd, a0.y * dd);
    o.y = pack2(a0.z * dd, a0.w * dd);
    o.z = pack2(a1.x * dd, a1.y * dd);
    o.w = pack2(a1.z * dd, a1.w * dd);
    *(uint4*)(zout + (size_t)node * 64u + c * 8u) = o;
}

// ---- final layer fused with l2norm: out = l2norm((z0+z1+z2+z3)/4) -----------
__global__ void spmm_final_kernel(const ushort_t* __restrict__ z0,
                                  const ushort_t* __restrict__ z1,
                                  const ushort_t* __restrict__ z2,
                                  const int2* __restrict__ packed,
                                  const int* __restrict__ offs,
                                  const float* __restrict__ dinv,
                                  float* __restrict__ out) {
    unsigned t = blockIdx.x * 256u + threadIdx.x;
    unsigned node = t >> 3, c = t & 7u;
    if (node >= NN) return;
    float4 a0 = make_float4(0,0,0,0), a1 = make_float4(0,0,0,0);
    gather_node8(z2, packed, offs[node], offs[node + 1], c, a0, a1);
    float d = dinv[node], dd = d * d;
    size_t ri = (size_t)node * 64u + c * 8u;
    uint4 p0 = *(const uint4*)(z0 + ri);
    uint4 p1 = *(const uint4*)(z1 + ri);
    uint4 p2 = *(const uint4*)(z2 + ri);
    float v[8];
    v[0] = lo16(p0.x) + lo16(p1.x) + lo16(p2.x) + a0.x * dd;
    v[1] = hi16(p0.x) + hi16(p1.x) + hi16(p2.x) + a0.y * dd;
    v[2] = lo16(p0.y) + lo16(p1.y) + lo16(p2.y) + a0.z * dd;
    v[3] = hi16(p0.y) + hi16(p1.y) + hi16(p2.y) + a0.w * dd;
    v[4] = lo16(p0.z) + lo16(p1.z) + lo16(p2.z) + a1.x * dd;
    v[5] = hi16(p0.z) + hi16(p1.z) + hi16(p2.z) + a1.y * dd;
    v[6] = lo16(p0.w) + lo16(p1.w) + lo16(p2.w) + a1.z * dd;
    v[7] = hi16(p0.w) + hi16(p1.w) + hi16(p2.w) + a1.w * dd;
    float s = 0.f;
#pragma unroll
    for (int k = 0; k < 8; ++k) s = fmaf(v[k], v[k], s);
    s += __shfl_xor(s, 1, 8);
    s += __shfl_xor(s, 2, 8);
    s += __shfl_xor(s, 4, 8);
    float n = fmaxf(sqrtf(s) * 0.25f, 1e-12f);    // norm of acc/4, ref eps
    float inv = 0.25f / n;
    float4 o0 = make_float4(v[0]*inv, v[1]*inv, v[2]*inv, v[3]*inv);
    float4 o1 = make_float4(v[4]*inv, v[5]*inv, v[6]*inv, v[7]*inv);
    *(float4*)(out + ri)     = o0;
    *(float4*)(out + ri + 4) = o1;
    if (t == 0) out[(size_t)NN * 64u] = 0.f;      // align_loss
}

extern "C" void kernel_launch(void* const* d_in, const int* in_sizes, int n_in,
                              void* d_out, int out_size, void* d_ws, size_t ws_size,
                              hipStream_t stream) {
    const float* user_w     = (const float*)d_in[0];
    const float* audio      = (const float*)d_in[1];
    const float* artist_w   = (const float*)d_in[2];
    const float* album_w    = (const float*)d_in[3];
    const float* w1         = (const float*)d_in[4];
    const float* b1         = (const float*)d_in[5];
    const float* w2         = (const float*)d_in[6];
    const float* b2         = (const float*)d_in[7];
    const float* feats      = (const float*)d_in[8];
    const int*   row        = (const int*)d_in[9];
    const int*   col        = row + EE;
    const int*   artist_ids = (const int*)d_in[10];
    const int*   album_ids  = (const int*)d_in[11];
    float* out = (float*)d_out;

    // workspace (4B units): counts[NNP] offs[NNP+16] partials[1024] rank[EE]
    //                        ew[EE] dinv[NN] packed[EE int2] z0..z2 bf16 ~79MB
    int*      counts   = (int*)d_ws;
    int*      offs     = counts + NNP;
    int*      partials = offs + NNP + 16;
    int*      rank     = partials + 1024;
    float*    ew       = (float*)(rank + EE);
    float*    dinv     = ew + EE;
    int2*     packed   = (int2*)(dinv + NN);
    ushort_t* z0       = (ushort_t*)(packed + EE);
    ushort_t* z1       = z0 + (size_t)NN * 64;
    ushort_t* z2       = z1 + (size_t)NN * 64;

    hipMemsetAsync(counts, 0, NNP * sizeof(int), stream);

    mlp_count_kernel<<<(EE + 255) / 256, 256, 0, stream>>>(feats, w1, b1, w2, b2,
                                                           col, ew, rank, counts);
    scan1_kernel<<<NB, 256, 0, stream>>>(counts, offs, partials);
    scan2_kernel<<<1, 256, 0, stream>>>(partials, NB);
    scan3_kernel<<<NB, 256, 0, stream>>>(offs, partials);
    fill_kernel<<<(EE + 255) / 256, 256, 0, stream>>>(ew, rank, row, col, offs, packed);
    dinv_init_kernel<<<G8_BLOCKS, 256, 0, stream>>>(packed, offs,
                                                    user_w, audio, artist_w, album_w,
                                                    artist_ids, album_ids, dinv, z0);
    spmm_kernel<<<G8_BLOCKS, 256, 0, stream>>>(z0, packed, offs, dinv, z1);
    spmm_kernel<<<G8_BLOCKS, 256, 0, stream>>>(z1, packed, offs, dinv, z2);
    spmm_final_kernel<<<G8_BLOCKS, 256, 0, stream>>>(z0, z1, z2, packed, offs,
                                                     dinv, out);
}

// Round 8
// 318.275 us; speedup vs baseline: 2.5726x; 1.0233x over previous
//
#include <hip/hip_runtime.h>
#include <math.h>

#define NUM_USERS 100000
#define NUM_ITEMS 50000
#define NN 150000               // total nodes
#define EE 1200000              // total directed edges (2 * E_DIR)
#define NB 586                  // ceil(NN/256) scan blocks
#define NNP (NB * 256)          // padded node count = 150016
#define G8_BLOCKS 4688          // ceil(NN*8/256) for 8-lane-per-node kernels

typedef unsigned short ushort_t;
typedef unsigned int uint_t;

__device__ __forceinline__ uint_t pack2(float lo, float hi) {   // 2x fp32 -> bf16x2 RNE
    uint_t a = __float_as_uint(lo);
    uint_t b = __float_as_uint(hi);
    a = (a + 0x7FFFu + ((a >> 16) & 1u)) >> 16;
    b = (b + 0x7FFFu + ((b >> 16) & 1u)) & 0xFFFF0000u;
    return a | b;
}
__device__ __forceinline__ float lo16(uint_t x) { return __uint_as_float(x << 16); }
__device__ __forceinline__ float hi16(uint_t x) { return __uint_as_float(x & 0xFFFF0000u); }

// ---- fused edge MLP + count/rank (ONE atomic per edge) ----------------------
// er[e] = {rank, ew_bits};  rank = counts[col[e]]++ (atomic return)
__global__ void mlp_count_kernel(const float* __restrict__ feats,
                                 const float* __restrict__ w1,
                                 const float* __restrict__ b1,
                                 const float* __restrict__ w2,
                                 const float* __restrict__ b2,
                                 const int* __restrict__ col,
                                 int2* __restrict__ er,
                                 int* __restrict__ counts) {
    __shared__ float sw1[256];
    __shared__ float sb1[32];
    __shared__ float sw2[32];
    __shared__ float sb2;
    int t = threadIdx.x;
    sw1[t] = w1[t];
    if (t < 32) { sb1[t] = b1[t]; sw2[t] = w2[t]; }
    if (t == 0) sb2 = b2[0];
    __syncthreads();
    int e = blockIdx.x * 256 + t;
    if (e >= EE) return;
    int c = col[e];
    const float4* fp = (const float4*)(feats + (size_t)e * 8);
    float4 fa = fp[0], fb = fp[1];
    float f[8] = {fa.x, fa.y, fa.z, fa.w, fb.x, fb.y, fb.z, fb.w};
    float s = sb2;
#pragma unroll
    for (int j = 0; j < 32; ++j) {
        float h = sb1[j];
#pragma unroll
        for (int i = 0; i < 8; ++i) h = fmaf(f[i], sw1[i * 32 + j], h);
        h = fmaxf(h, 0.f);
        s = fmaf(h, sw2[j], s);
    }
    float w = 1.f / (1.f + expf(-s));
    int k = atomicAdd(&counts[c], 1);
    er[e] = make_int2(k, __float_as_int(w));
}

// ---- scan step 1: per-block exclusive scan of counts; block totals ----------
__global__ void scan1_kernel(const int* __restrict__ counts,
                             int* __restrict__ offs,
                             int* __restrict__ partials) {
    int i = blockIdx.x * 256 + threadIdx.x;
    int lane = threadIdx.x & 63;
    int v = counts[i];                           // [NN,NNP) pre-zeroed
    int s = v;
#pragma unroll
    for (int off = 1; off < 64; off <<= 1) {
        int u = __shfl_up(s, off, 64);
        if (lane >= off) s += u;
    }
    __shared__ int wsum[4];
    if (lane == 63) wsum[threadIdx.x >> 6] = s;
    __syncthreads();
    int add = 0;
    for (int w = 0; w < (threadIdx.x >> 6); ++w) add += wsum[w];
    offs[i] = s - v + add;
    if (threadIdx.x == 255) partials[blockIdx.x] = s + add;
}

// ---- scan step 2+3 fused: every block scans partials in LDS, adds its base --
__global__ void scan23_kernel(int* __restrict__ offs,
                              const int* __restrict__ partials) {
    __shared__ int sp[768];                      // NB=586 padded to 768 = 256*3
    __shared__ int wsum[4];
    int t = threadIdx.x;
#pragma unroll
    for (int k = 0; k < 3; ++k) {
        int idx = t + k * 256;
        sp[idx] = (idx < NB) ? partials[idx] : 0;
    }
    __syncthreads();
    int v0 = sp[3 * t], v1 = sp[3 * t + 1], v2 = sp[3 * t + 2];
    int tot = v0 + v1 + v2;
    int lane = t & 63;
    int s = tot;
#pragma unroll
    for (int off = 1; off < 64; off <<= 1) {
        int u = __shfl_up(s, off, 64);
        if (lane >= off) s += u;
    }
    if (lane == 63) wsum[t >> 6] = s;
    __syncthreads();
    int add = 0;
    for (int w = 0; w < (t >> 6); ++w) add += wsum[w];
    int excl = s - tot + add;
    sp[3 * t]     = excl;
    sp[3 * t + 1] = excl + v0;
    sp[3 * t + 2] = excl + v0 + v1;
    __syncthreads();
    int base = sp[blockIdx.x];                   // exclusive prefix of totals
    int i = blockIdx.x * 256 + t;
    offs[i] = offs[i] + base;
}

// ---- atomic-free CSR fill: packed[offs[col]+rank] = {row, ew} ---------------
__global__ void fill_kernel(const int2* __restrict__ er,
                            const int* __restrict__ row,
                            const int* __restrict__ col,
                            const int* __restrict__ offs,
                            int2* __restrict__ packed) {
    int e = blockIdx.x * 256 + threadIdx.x;
    if (e >= EE) return;
    int2 p = er[e];
    int slot = offs[col[e]] + p.x;
    packed[slot] = make_int2(row[e], p.y);
}

// ---- gather core: 8 lanes per node, 16B loads; a0/a1 = cols 8c..8c+7 --------
__device__ __forceinline__ void gather_node8(const ushort_t* __restrict__ zin,
                                             const int2* __restrict__ packed,
                                             int beg, int end, unsigned c,
                                             float4& a0, float4& a1) {
    for (int base = beg; base < end; base += 8) {
        int m = end - base; if (m > 8) m = 8;
        int r = 0; float w = 0.f;
        if ((int)c < m) {
            int2 p = packed[base + (int)c];
            r = p.x; w = __int_as_float(p.y);
        }
        int rj[8]; float wj[8]; uint4 vj[8];
#pragma unroll
        for (int u = 0; u < 8; ++u) {
            int idx = (u < m) ? u : (m - 1);       // clamp: re-read last valid row
            rj[u] = __shfl(r, idx, 8);
            wj[u] = __shfl(w, u, 8);               // lanes >= m carry w=0
        }
#pragma unroll
        for (int u = 0; u < 8; ++u)
            vj[u] = *(const uint4*)(zin + (size_t)(uint_t)rj[u] * 64u + c * 8u);
#pragma unroll
        for (int u = 0; u < 8; ++u) {
            float ww = wj[u]; uint4 v = vj[u];
            a0.x = fmaf(ww, lo16(v.x), a0.x);
            a0.y = fmaf(ww, hi16(v.x), a0.y);
            a0.z = fmaf(ww, lo16(v.y), a0.z);
            a0.w = fmaf(ww, hi16(v.y), a0.w);
            a1.x = fmaf(ww, lo16(v.z), a1.x);
            a1.y = fmaf(ww, hi16(v.z), a1.y);
            a1.z = fmaf(ww, lo16(v.w), a1.z);
            a1.w = fmaf(ww, hi16(v.w), a1.w);
        }
    }
}

// ---- fused dinv + z0 (8 lanes per node) -------------------------------------
__global__ void dinv_init_kernel(const int2* __restrict__ packed,
                                 const int* __restrict__ offs,
                                 const float* __restrict__ user_w,
                                 const float* __restrict__ audio,
                                 const float* __restrict__ artist_w,
                                 const float* __restrict__ album_w,
                                 const int* __restrict__ artist_ids,
                                 const int* __restrict__ album_ids,
                                 float* __restrict__ dinv,
                                 ushort_t* __restrict__ z0) {
    unsigned t = blockIdx.x * 256u + threadIdx.x;
    unsigned node = t >> 3, c = t & 7u;
    if (node >= NN) return;
    int beg = offs[node], end = offs[node + 1];
    float ds = 0.f;
    for (int k = beg + (int)c; k < end; k += 8) ds += __int_as_float(packed[k].y);
    ds += __shfl_xor(ds, 1, 8);
    ds += __shfl_xor(ds, 2, 8);
    ds += __shfl_xor(ds, 4, 8);
    float d = (ds > 0.f) ? rsqrtf(ds) : 0.f;
    if (c == 0) dinv[node] = d;

    size_t ri = (size_t)node * 64u + c * 8u;
    float v[8];
    if (node < NUM_USERS) {
        float4 x0 = *(const float4*)(user_w + ri);
        float4 x1 = *(const float4*)(user_w + ri + 4);
        v[0]=x0.x; v[1]=x0.y; v[2]=x0.z; v[3]=x0.w;
        v[4]=x1.x; v[5]=x1.y; v[6]=x1.z; v[7]=x1.w;
    } else {
        unsigned j = node - NUM_USERS;
        unsigned aid = (unsigned)artist_ids[j], bid = (unsigned)album_ids[j];
        const float* ap = artist_w + (size_t)aid * 64u + c * 8u;
        const float* bp = album_w  + (size_t)bid * 64u + c * 8u;
        const float* up = audio    + (size_t)j   * 64u + c * 8u;
        float4 A0 = *(const float4*)ap, A1 = *(const float4*)(ap + 4);
        float4 B0 = *(const float4*)bp, B1 = *(const float4*)(bp + 4);
        float4 U0 = *(const float4*)up, U1 = *(const float4*)(up + 4);
        v[0] = fmaf(0.44f, A0.x + B0.x, 0.3f * U0.x);
        v[1] = fmaf(0.44f, A0.y + B0.y, 0.3f * U0.y);
        v[2] = fmaf(0.44f, A0.z + B0.z, 0.3f * U0.z);
        v[3] = fmaf(0.44f, A0.w + B0.w, 0.3f * U0.w);
        v[4] = fmaf(0.44f, A1.x + B1.x, 0.3f * U1.x);
        v[5] = fmaf(0.44f, A1.y + B1.y, 0.3f * U1.y);
        v[6] = fmaf(0.44f, A1.z + B1.z, 0.3f * U1.z);
        v[7] = fmaf(0.44f, A1.w + B1.w, 0.3f * U1.w);
    }
    float s = 0.f;
#pragma unroll
    for (int k = 0; k < 8; ++k) s = fmaf(v[k], v[k], s);
    s += __shfl_xor(s, 1, 8);
    s += __shfl_xor(s, 2, 8);
    s += __shfl_xor(s, 4, 8);
    float rn = rsqrtf(fmaxf(s, 1e-24f));          // == 1/max(||x||,1e-12)
    float scale = ((d > 0.f) ? d : 1.f) * rn;
    uint4 o;
    o.x = pack2(v[0] * scale, v[1] * scale);
    o.y = pack2(v[2] * scale, v[3] * scale);
    o.z = pack2(v[4] * scale, v[5] * scale);
    o.w = pack2(v[6] * scale, v[7] * scale);
    *(uint4*)(z0 + ri) = o;
}

// ---- SpMM layer in z-space: zout[n] = dinv_n^2 * sum ew * zin[row] ----------
__global__ void spmm_kernel(const ushort_t* __restrict__ zin,
                            const int2* __restrict__ packed,
                            const int* __restrict__ offs,
                            const float* __restrict__ dinv,
                            ushort_t* __restrict__ zout) {
    unsigned t = blockIdx.x * 256u + threadIdx.x;
    unsigned node = t >> 3, c = t & 7u;
    if (node >= NN) return;
    float4 a0 = make_float4(0,0,0,0), a1 = make_float4(0,0,0,0);
    gather_node8(zin, packed, offs[node], offs[node + 1], c, a0, a1);
    float d = dinv[node], dd = d * d;
    uint4 o;
    o.x = pack2(a0.x * dd, a0.y * dd);
    o.y = pack2(a0.z * dd, a0.w * dd);
    o.z = pack2(a1.x * dd, a1.y * dd);
    o.w = pack2(a1.z * dd, a1.w * dd);
    *(uint4*)(zout + (size_t)node * 64u + c * 8u) = o;
}

// ---- final layer fused with l2norm: out = l2norm((z0+z1+z2+z3)/4) -----------
__global__ void spmm_final_kernel(const ushort_t* __restrict__ z0,
                                  const ushort_t* __restrict__ z1,
                                  const ushort_t* __restrict__ z2,
                                  const int2* __restrict__ packed,
                                  const int* __restrict__ offs,
                                  const float* __restrict__ dinv,
                                  float* __restrict__ out) {
    unsigned t = blockIdx.x * 256u + threadIdx.x;
    unsigned node = t >> 3, c = t & 7u;
    if (node >= NN) return;
    float4 a0 = make_float4(0,0,0,0), a1 = make_float4(0,0,0,0);
    gather_node8(z2, packed, offs[node], offs[node + 1], c, a0, a1);
    float d = dinv[node], dd = d * d;
    size_t ri = (size_t)node * 64u + c * 8u;
    uint4 p0 = *(const uint4*)(z0 + ri);
    uint4 p1 = *(const uint4*)(z1 + ri);
    uint4 p2 = *(const uint4*)(z2 + ri);
    float v[8];
    v[0] = lo16(p0.x) + lo16(p1.x) + lo16(p2.x) + a0.x * dd;
    v[1] = hi16(p0.x) + hi16(p1.x) + hi16(p2.x) + a0.y * dd;
    v[2] = lo16(p0.y) + lo16(p1.y) + lo16(p2.y) + a0.z * dd;
    v[3] = hi16(p0.y) + hi16(p1.y) + hi16(p2.y) + a0.w * dd;
    v[4] = lo16(p0.z) + lo16(p1.z) + lo16(p2.z) + a1.x * dd;
    v[5] = hi16(p0.z) + hi16(p1.z) + hi16(p2.z) + a1.y * dd;
    v[6] = lo16(p0.w) + lo16(p1.w) + lo16(p2.w) + a1.z * dd;
    v[7] = hi16(p0.w) + hi16(p1.w) + hi16(p2.w) + a1.w * dd;
    float s = 0.f;
#pragma unroll
    for (int k = 0; k < 8; ++k) s = fmaf(v[k], v[k], s);
    s += __shfl_xor(s, 1, 8);
    s += __shfl_xor(s, 2, 8);
    s += __shfl_xor(s, 4, 8);
    float n = fmaxf(sqrtf(s) * 0.25f, 1e-12f);    // norm of acc/4, ref eps
    float inv = 0.25f / n;
    float4 o0 = make_float4(v[0]*inv, v[1]*inv, v[2]*inv, v[3]*inv);
    float4 o1 = make_float4(v[4]*inv, v[5]*inv, v[6]*inv, v[7]*inv);
    *(float4*)(out + ri)     = o0;
    *(float4*)(out + ri + 4) = o1;
    if (t == 0) out[(size_t)NN * 64u] = 0.f;      // align_loss
}

extern "C" void kernel_launch(void* const* d_in, const int* in_sizes, int n_in,
                              void* d_out, int out_size, void* d_ws, size_t ws_size,
                              hipStream_t stream) {
    const float* user_w     = (const float*)d_in[0];
    const float* audio      = (const float*)d_in[1];
    const float* artist_w   = (const float*)d_in[2];
    const float* album_w    = (const float*)d_in[3];
    const float* w1         = (const float*)d_in[4];
    const float* b1         = (const float*)d_in[5];
    const float* w2         = (const float*)d_in[6];
    const float* b2         = (const float*)d_in[7];
    const float* feats      = (const float*)d_in[8];
    const int*   row        = (const int*)d_in[9];
    const int*   col        = row + EE;
    const int*   artist_ids = (const int*)d_in[10];
    const int*   album_ids  = (const int*)d_in[11];
    float* out = (float*)d_out;

    // workspace (4B units): counts[NNP] offs[NNP+16] partials[1024]
    //                        er[EE int2] dinv[NN] packed[EE int2] z0..z2 ~79MB
    int*      counts   = (int*)d_ws;
    int*      offs     = counts + NNP;
    int*      partials = offs + NNP + 16;
    int2*     er       = (int2*)(partials + 1024);
    float*    dinv     = (float*)(er + EE);
    int2*     packed   = (int2*)(dinv + NN);
    ushort_t* z0       = (ushort_t*)(packed + EE);
    ushort_t* z1       = z0 + (size_t)NN * 64;
    ushort_t* z2       = z1 + (size_t)NN * 64;

    hipMemsetAsync(counts, 0, NNP * sizeof(int), stream);

    mlp_count_kernel<<<(EE + 255) / 256, 256, 0, stream>>>(feats, w1, b1, w2, b2,
                                                           col, er, counts);
    scan1_kernel<<<NB, 256, 0, stream>>>(counts, offs, partials);
    scan23_kernel<<<NB, 256, 0, stream>>>(offs, partials);
    fill_kernel<<<(EE + 255) / 256, 256, 0, stream>>>(er, row, col, offs, packed);
    dinv_init_kernel<<<G8_BLOCKS, 256, 0, stream>>>(packed, offs,
                                                    user_w, audio, artist_w, album_w,
                                                    artist_ids, album_ids, dinv, z0);
    spmm_kernel<<<G8_BLOCKS, 256, 0, stream>>>(z0, packed, offs, dinv, z1);
    spmm_kernel<<<G8_BLOCKS, 256, 0, stream>>>(z1, packed, offs, dinv, z2);
    spmm_final_kernel<<<G8_BLOCKS, 256, 0, stream>>>(z0, z1, z2, packed, offs,
                                                     dinv, out);
}